// Round 1
// baseline (1066.388 us; speedup 1.0000x reference)
//
#include <hip/hip_runtime.h>
#include <cstdint>

// Problem constants
#define E_ 8
#define D_ 1024
#define H_ 4096
#define NTOK 16384   // B*S = 4*4096

typedef unsigned short ushort_t;
typedef __attribute__((ext_vector_type(8))) short short8;
typedef __attribute__((ext_vector_type(4))) float f32x4;

__device__ __forceinline__ ushort_t f2bf(float f) {
  uint32_t u = __builtin_bit_cast(uint32_t, f);
  uint32_t r = (u + 0x7fffu + ((u >> 16) & 1u)) >> 16;  // RNE
  return (ushort_t)r;
}

__device__ __forceinline__ void gload_lds16(const void* g, void* l) {
  __builtin_amdgcn_global_load_lds(
      (const __attribute__((address_space(1))) uint32_t*)g,
      (__attribute__((address_space(3))) uint32_t*)l, 16, 0, 0);
}

// ---------------- init: zero counts/cursor + rawbase ----------------
__global__ void init_kernel(int* counts_cursor, float* rawbase) {
  int tid = threadIdx.x + blockIdx.x * 256;
  if (tid < 16) counts_cursor[tid] = 0;
  if (tid < E_ * D_) rawbase[tid] = 0.f;   // grid 32*256 = 8192 threads
}

// ---------------- transpose fp32 [E][R][C] -> bf16 [E][C][R] ----------------
__global__ void transpose_bf16(const float* __restrict__ in, ushort_t* __restrict__ out,
                               int R, int C) {
  __shared__ float t[32][33];
  const int e = blockIdx.z;
  const float* ip = in + (size_t)e * R * C;
  ushort_t* op = out + (size_t)e * R * C;
  const int c0 = blockIdx.x * 32, r0 = blockIdx.y * 32;
  const int tx = threadIdx.x, ty = threadIdx.y;
#pragma unroll
  for (int q = 0; q < 4; ++q)
    t[ty + q * 8][tx] = ip[(size_t)(r0 + ty + q * 8) * C + c0 + tx];
  __syncthreads();
#pragma unroll
  for (int q = 0; q < 4; ++q) {
    int c = c0 + ty + q * 8;
    op[(size_t)c * R + r0 + tx] = f2bf(t[tx][ty + q * 8]);
  }
}

// ---------------- per-expert base vector: rawbase[e][d] = sum_h relu(b1[e][h]) * W2[e][h][d] ----------------
__global__ void base_kernel(const float* __restrict__ b1, const float* __restrict__ W2,
                            float* __restrict__ rawbase) {
  const int e = blockIdx.y;
  const int d = blockIdx.x * 256 + threadIdx.x;
  const int h0 = blockIdx.z * 512;
  const float* w = W2 + (size_t)e * H_ * D_ + (size_t)h0 * D_ + d;
  const float* b = b1 + e * H_ + h0;
  float s = 0.f;
#pragma unroll 4
  for (int h = 0; h < 512; ++h) {
    float hv = fmaxf(b[h], 0.f);
    s += hv * w[(size_t)h * D_];
  }
  atomicAdd(&rawbase[e * D_ + d], s);
}

// adj[e][d] = sum_i (rawbase[i][d] + b2[i][d]) - rawbase[e][d]
__global__ void adj_kernel(const float* __restrict__ rawbase, const float* __restrict__ b2,
                           float* __restrict__ adj) {
  int i = blockIdx.x * 256 + threadIdx.x;  // 8192
  int d = i & (D_ - 1);
  int e = i >> 10;
  float tot = 0.f;
#pragma unroll
  for (int ii = 0; ii < E_; ++ii) tot += rawbase[ii * D_ + d] + b2[ii * D_ + d];
  adj[i] = tot - rawbase[e * D_ + d];
}

// ---------------- router: fp32 logits -> argmax (first-max tiebreak), count per expert ----------------
__global__ void router_kernel(const float* __restrict__ x, const float* __restrict__ Wr,
                              const float* __restrict__ br, int* __restrict__ idx,
                              int* __restrict__ counts) {
  __shared__ float wr_s[E_][D_];   // transposed Wr: wr_s[e][d]
  const int tid = threadIdx.x;
  for (int j = tid; j < E_ * D_; j += 256) {
    int e = j & 7, d = j >> 3;
    wr_s[e][d] = Wr[j];
  }
  __syncthreads();
  const int wid = tid >> 6, l = tid & 63;
  const int t0 = blockIdx.x * 32 + wid * 8;
  for (int tt = 0; tt < 8; ++tt) {
    int t = t0 + tt;
    const float* xr = x + (size_t)t * D_;
    float s[E_];
#pragma unroll
    for (int e = 0; e < E_; ++e) s[e] = 0.f;
    for (int q = 0; q < D_ / 64; ++q) {
      float xv = xr[q * 64 + l];
#pragma unroll
      for (int e = 0; e < E_; ++e) s[e] += xv * wr_s[e][q * 64 + l];
    }
#pragma unroll
    for (int e = 0; e < E_; ++e) {
#pragma unroll
      for (int off = 32; off > 0; off >>= 1) s[e] += __shfl_xor(s[e], off, 64);
    }
    if (l == 0) {
      float best = s[0] + br[0];
      int bi = 0;
#pragma unroll
      for (int e = 1; e < E_; ++e) {
        float v = s[e] + br[e];
        if (v > best) { best = v; bi = e; }   // strict >: first-max like argmax
      }
      idx[t] = bi;
      atomicAdd(&counts[bi], 1);
    }
  }
}

// ---------------- tiny scan: offsets[0..E] ----------------
__global__ void scan_kernel(const int* __restrict__ counts, int* __restrict__ offsets) {
  if (threadIdx.x == 0 && blockIdx.x == 0) {
    int acc = 0;
    for (int e = 0; e < E_; ++e) { offsets[e] = acc; acc += counts[e]; }
    offsets[E_] = acc;
  }
}

// ---------------- scatter: counting-sort tokens, gather x -> bf16 xg ----------------
__global__ void scatter_kernel(const float* __restrict__ x, const int* __restrict__ idx,
                               const int* __restrict__ offsets, int* __restrict__ cursor,
                               int* __restrict__ perm, ushort_t* __restrict__ xg) {
  const int tid = threadIdx.x;
  const int wid = tid >> 6, l = tid & 63;
  const int t = blockIdx.x * 4 + wid;
  int e = idx[t];
  int slot = 0;
  if (l == 0) {
    slot = offsets[e] + atomicAdd(&cursor[e], 1);
    perm[slot] = t;
  }
  slot = __shfl(slot, 0, 64);
  const float4* xr = (const float4*)(x + (size_t)t * D_);
  ushort_t* xo = xg + (size_t)slot * D_;
#pragma unroll
  for (int q = 0; q < 4; ++q) {
    float4 v = xr[q * 64 + l];
    ushort4 o;
    o.x = f2bf(v.x); o.y = f2bf(v.y); o.z = f2bf(v.z); o.w = f2bf(v.w);
    *(ushort4*)(xo + (size_t)(q * 64 + l) * 4) = o;
  }
}

// ---------------- grouped GEMM: 128x128 tile, BK=64, bf16 MFMA 16x16x32 ----------------
// MODE 1: hb = relu(xg @ W1t^T + b1) (bf16 out) ; MODE 2: out[perm] = hb @ W2t^T + adj (f32)
// A: row-major [M][Kd] bf16 (gathered). B: row-major [Nd][Kd] bf16 (pre-transposed weights).
// LDS tiles [128][64] with T2-style XOR swizzle: LDS[row][v] holds global 16B-unit v^(row&7),
// achieved via pre-swizzled global source addresses (global_load_lds dest stays linear).
template <int MODE>
__global__ __launch_bounds__(256) void ffn_gemm(
    const ushort_t* __restrict__ A_all, const ushort_t* __restrict__ Bw,
    const float* __restrict__ bias, const int* __restrict__ offs,
    const int* __restrict__ perm, float* __restrict__ out, ushort_t* __restrict__ hb) {
  constexpr int Kd = (MODE == 1) ? D_ : H_;
  constexpr int Nd = (MODE == 1) ? H_ : D_;
  constexpr int TN = Nd / 128;
  const int e = blockIdx.y;
  const int ms = offs[e];
  const int M = offs[e + 1] - ms;
  const int tm = blockIdx.x / TN;
  if (tm * 128 >= M) return;
  const int tn = blockIdx.x % TN;

  __shared__ __align__(16) ushort_t lA[128 * 64];
  __shared__ __align__(16) ushort_t lB[128 * 64];

  const int tid = threadIdx.x;
  const int wid = tid >> 6, l = tid & 63;
  const int srow = l >> 3;             // row within 8-row staging chunk
  const int sunit = (l & 7) ^ srow;    // pre-swizzled global 16B-unit

  const ushort_t* Ab = A_all + (size_t)ms * Kd;
  const ushort_t* Bb = Bw + (size_t)e * ((size_t)Nd * Kd);

  const ushort_t* aptr[4];
  const ushort_t* bptr[4];
  int lof[4];
#pragma unroll
  for (int c = 0; c < 4; ++c) {
    int chunk = wid * 4 + c;           // 0..15
    int rt = chunk * 8 + srow;         // tile row 0..127
    int gm = tm * 128 + rt;
    if (gm > M - 1) gm = M - 1;        // clamp ragged tail (stores guarded)
    aptr[c] = Ab + (size_t)gm * Kd + sunit * 8;
    int gn = tn * 128 + rt;            // Nd is a multiple of 128
    bptr[c] = Bb + (size_t)gn * Kd + sunit * 8;
    lof[c] = chunk * 512;              // ushort offset = 1KB per chunk
  }

  f32x4 acc[4][4];
#pragma unroll
  for (int i = 0; i < 4; ++i)
#pragma unroll
    for (int j = 0; j < 4; ++j) acc[i][j] = (f32x4){0.f, 0.f, 0.f, 0.f};

  const int wr = (wid >> 1) * 64;
  const int wc = (wid & 1) * 64;
  const int lr = l & 15;
  const int lh = l >> 4;   // 0..3
  const int lx = l & 7;    // read-side XOR factor (= row&7)

  for (int kt = 0; kt < Kd / 64; ++kt) {
#pragma unroll
    for (int c = 0; c < 4; ++c) gload_lds16(aptr[c] + kt * 64, &lA[lof[c]]);
#pragma unroll
    for (int c = 0; c < 4; ++c) gload_lds16(bptr[c] + kt * 64, &lB[lof[c]]);
    __syncthreads();   // compiler drains vmcnt before barrier
#pragma unroll
    for (int ks = 0; ks < 2; ++ks) {
      short8 af[4], bfv[4];
      const int u = (ks * 4 + lh) ^ lx;
#pragma unroll
      for (int i = 0; i < 4; ++i) {
        int row = wr + i * 16 + lr;
        af[i] = *(const short8*)&lA[row * 64 + u * 8];
      }
#pragma unroll
      for (int j = 0; j < 4; ++j) {
        int row = wc + j * 16 + lr;
        bfv[j] = *(const short8*)&lB[row * 64 + u * 8];
      }
#pragma unroll
      for (int i = 0; i < 4; ++i)
#pragma unroll
        for (int j = 0; j < 4; ++j)
          acc[i][j] = __builtin_amdgcn_mfma_f32_16x16x32_bf16(af[i], bfv[j], acc[i][j], 0, 0, 0);
    }
    __syncthreads();
  }

  // epilogue: C[m = wr+i*16+lh*4+r][n = wc+j*16+lr]
  float bv[4];
  const int gcolbase = tn * 128 + wc + lr;
#pragma unroll
  for (int j = 0; j < 4; ++j) bv[j] = bias[e * Nd + gcolbase + j * 16];
#pragma unroll
  for (int i = 0; i < 4; ++i) {
#pragma unroll
    for (int r = 0; r < 4; ++r) {
      int grow = tm * 128 + wr + i * 16 + lh * 4 + r;
      if (grow < M) {
        if (MODE == 1) {
          size_t rowoff = (size_t)(ms + grow) * H_;
#pragma unroll
          for (int j = 0; j < 4; ++j) {
            float v = acc[i][j][r] + bv[j];
            v = fmaxf(v, 0.f);
            hb[rowoff + gcolbase + j * 16] = f2bf(v);
          }
        } else {
          int tok = perm[ms + grow];
          size_t rowoff = (size_t)tok * D_;
#pragma unroll
          for (int j = 0; j < 4; ++j) out[rowoff + gcolbase + j * 16] = acc[i][j][r] + bv[j];
        }
      }
    }
  }
}

extern "C" void kernel_launch(void* const* d_in, const int* in_sizes, int n_in,
                              void* d_out, int out_size, void* d_ws, size_t ws_size,
                              hipStream_t stream) {
  const float* x  = (const float*)d_in[0];
  const float* W1 = (const float*)d_in[1];
  const float* b1 = (const float*)d_in[2];
  const float* W2 = (const float*)d_in[3];
  const float* b2 = (const float*)d_in[4];
  const float* Wr = (const float*)d_in[5];
  const float* br = (const float*)d_in[6];
  float* out = (float*)d_out;

  // workspace layout (needs ~302.3 MB)
  char* ws = (char*)d_ws;
  ushort_t* W1t   = (ushort_t*)(ws);                    // [E][H][D] bf16: 67108864 B
  ushort_t* W2t   = (ushort_t*)(ws + 67108864);         // [E][D][H] bf16: 67108864 B
  ushort_t* xg    = (ushort_t*)(ws + 134217728);        // [N][D]   bf16: 33554432 B
  ushort_t* hb    = (ushort_t*)(ws + 167772160);        // [N][H]   bf16: 134217728 B
  float*    rawbase = (float*)(ws + 301989888);         // [E][D] f32
  float*    adj   = (float*)(ws + 302022656);           // [E][D] f32
  int*      idx   = (int*)(ws + 302055424);             // [N]
  int*      perm  = (int*)(ws + 302120960);             // [N]
  int*      counts = (int*)(ws + 302186496);            // 8 + 8 cursor
  int*      cursor = counts + 8;
  int*      offsets = (int*)(ws + 302186624);           // 9

  init_kernel<<<32, 256, 0, stream>>>(counts, rawbase);
  transpose_bf16<<<dim3(H_ / 32, D_ / 32, E_), dim3(32, 8), 0, stream>>>(W1, W1t, D_, H_);
  transpose_bf16<<<dim3(D_ / 32, H_ / 32, E_), dim3(32, 8), 0, stream>>>(W2, W2t, H_, D_);
  base_kernel<<<dim3(4, E_, 8), 256, 0, stream>>>(b1, W2, rawbase);
  adj_kernel<<<32, 256, 0, stream>>>(rawbase, b2, adj);
  router_kernel<<<512, 256, 0, stream>>>(x, Wr, br, idx, counts);
  scan_kernel<<<1, 64, 0, stream>>>(counts, offsets);
  scatter_kernel<<<NTOK / 4, 256, 0, stream>>>(x, idx, offsets, cursor, perm, xg);
  ffn_gemm<1><<<dim3((NTOK / 128) * (H_ / 128), E_), 256, 0, stream>>>(
      xg, W1t, b1, offsets, nullptr, nullptr, hb);
  ffn_gemm<2><<<dim3((NTOK / 128) * (D_ / 128), E_), 256, 0, stream>>>(
      hb, W2t, adj, offsets, perm, out, nullptr);
}

// Round 2
// 1065.577 us; speedup vs baseline: 1.0008x; 1.0008x over previous
//
#include <hip/hip_runtime.h>
#include <cstdint>

// Problem constants
#define E_ 8
#define D_ 1024
#define H_ 4096
#define NTOK 16384   // B*S = 4*4096

typedef unsigned short ushort_t;
typedef __attribute__((ext_vector_type(8))) short short8;
typedef __attribute__((ext_vector_type(4))) float f32x4;

__device__ __forceinline__ ushort_t f2bf(float f) {
  uint32_t u = __builtin_bit_cast(uint32_t, f);
  uint32_t r = (u + 0x7fffu + ((u >> 16) & 1u)) >> 16;  // RNE
  return (ushort_t)r;
}

__device__ __forceinline__ void gload_lds16(const void* g, void* l) {
  __builtin_amdgcn_global_load_lds(
      (const __attribute__((address_space(1))) uint32_t*)g,
      (__attribute__((address_space(3))) uint32_t*)l, 16, 0, 0);
}

// ---------------- init: zero counts/cursor + rawbase ----------------
__global__ void init_kernel(int* counts_cursor, float* rawbase) {
  int tid = threadIdx.x + blockIdx.x * 256;
  if (tid < 16) counts_cursor[tid] = 0;
  if (tid < E_ * D_) rawbase[tid] = 0.f;   // grid 32*256 = 8192 threads
}

// ---------------- transpose fp32 [E][R][C] -> bf16 [E][C][R] ----------------
__global__ void transpose_bf16(const float* __restrict__ in, ushort_t* __restrict__ out,
                               int R, int C) {
  __shared__ float t[32][33];
  const int e = blockIdx.z;
  const float* ip = in + (size_t)e * R * C;
  ushort_t* op = out + (size_t)e * R * C;
  const int c0 = blockIdx.x * 32, r0 = blockIdx.y * 32;
  const int tx = threadIdx.x, ty = threadIdx.y;
#pragma unroll
  for (int q = 0; q < 4; ++q)
    t[ty + q * 8][tx] = ip[(size_t)(r0 + ty + q * 8) * C + c0 + tx];
  __syncthreads();
#pragma unroll
  for (int q = 0; q < 4; ++q) {
    int c = c0 + ty + q * 8;
    op[(size_t)c * R + r0 + tx] = f2bf(t[tx][ty + q * 8]);
  }
}

// ---------------- per-expert base vector: rawbase[e][d] = sum_h relu(b1[e][h]) * W2[e][h][d] ----------------
__global__ void base_kernel(const float* __restrict__ b1, const float* __restrict__ W2,
                            float* __restrict__ rawbase) {
  const int e = blockIdx.y;
  const int d = blockIdx.x * 256 + threadIdx.x;
  const int h0 = blockIdx.z * 512;
  const float* w = W2 + (size_t)e * H_ * D_ + (size_t)h0 * D_ + d;
  const float* b = b1 + e * H_ + h0;
  float s = 0.f;
#pragma unroll 4
  for (int h = 0; h < 512; ++h) {
    float hv = fmaxf(b[h], 0.f);
    s += hv * w[(size_t)h * D_];
  }
  atomicAdd(&rawbase[e * D_ + d], s);
}

// adj[e][d] = sum_i (rawbase[i][d] + b2[i][d]) - rawbase[e][d]
__global__ void adj_kernel(const float* __restrict__ rawbase, const float* __restrict__ b2,
                           float* __restrict__ adj) {
  int i = blockIdx.x * 256 + threadIdx.x;  // 8192
  int d = i & (D_ - 1);
  int e = i >> 10;
  float tot = 0.f;
#pragma unroll
  for (int ii = 0; ii < E_; ++ii) tot += rawbase[ii * D_ + d] + b2[ii * D_ + d];
  adj[i] = tot - rawbase[e * D_ + d];
}

// ---------------- router: fp32 logits -> argmax (first-max tiebreak), count per expert ----------------
__global__ void router_kernel(const float* __restrict__ x, const float* __restrict__ Wr,
                              const float* __restrict__ br, int* __restrict__ idx,
                              int* __restrict__ counts) {
  __shared__ float wr_s[E_][D_];   // transposed Wr: wr_s[e][d]
  const int tid = threadIdx.x;
  for (int j = tid; j < E_ * D_; j += 256) {
    int e = j & 7, d = j >> 3;
    wr_s[e][d] = Wr[j];
  }
  __syncthreads();
  const int wid = tid >> 6, l = tid & 63;
  const int t0 = blockIdx.x * 32 + wid * 8;
  for (int tt = 0; tt < 8; ++tt) {
    int t = t0 + tt;
    const float* xr = x + (size_t)t * D_;
    float s[E_];
#pragma unroll
    for (int e = 0; e < E_; ++e) s[e] = 0.f;
    for (int q = 0; q < D_ / 64; ++q) {
      float xv = xr[q * 64 + l];
#pragma unroll
      for (int e = 0; e < E_; ++e) s[e] += xv * wr_s[e][q * 64 + l];
    }
#pragma unroll
    for (int e = 0; e < E_; ++e) {
#pragma unroll
      for (int off = 32; off > 0; off >>= 1) s[e] += __shfl_xor(s[e], off, 64);
    }
    if (l == 0) {
      float best = s[0] + br[0];
      int bi = 0;
#pragma unroll
      for (int e = 1; e < E_; ++e) {
        float v = s[e] + br[e];
        if (v > best) { best = v; bi = e; }   // strict >: first-max like argmax
      }
      idx[t] = bi;
      atomicAdd(&counts[bi], 1);
    }
  }
}

// ---------------- tiny scan: offsets[0..E] ----------------
__global__ void scan_kernel(const int* __restrict__ counts, int* __restrict__ offsets) {
  if (threadIdx.x == 0 && blockIdx.x == 0) {
    int acc = 0;
    for (int e = 0; e < E_; ++e) { offsets[e] = acc; acc += counts[e]; }
    offsets[E_] = acc;
  }
}

// ---------------- scatter: counting-sort tokens, gather x -> bf16 xg ----------------
__global__ void scatter_kernel(const float* __restrict__ x, const int* __restrict__ idx,
                               const int* __restrict__ offsets, int* __restrict__ cursor,
                               int* __restrict__ perm, ushort_t* __restrict__ xg) {
  const int tid = threadIdx.x;
  const int wid = tid >> 6, l = tid & 63;
  const int t = blockIdx.x * 4 + wid;
  int e = idx[t];
  int slot = 0;
  if (l == 0) {
    slot = offsets[e] + atomicAdd(&cursor[e], 1);
    perm[slot] = t;
  }
  slot = __shfl(slot, 0, 64);
  const float4* xr = (const float4*)(x + (size_t)t * D_);
  ushort_t* xo = xg + (size_t)slot * D_;
#pragma unroll
  for (int q = 0; q < 4; ++q) {
    float4 v = xr[q * 64 + l];
    ushort4 o;
    o.x = f2bf(v.x); o.y = f2bf(v.y); o.z = f2bf(v.z); o.w = f2bf(v.w);
    *(ushort4*)(xo + (size_t)(q * 64 + l) * 4) = o;
  }
}

// ---------------- grouped GEMM: 256x256 tile, BK=64, 8-phase schedule ----------------
// 512 threads = 8 waves (2 M x 4 N). LDS: 2 bufs x {A0,A1,B0,B1} halves of [128][64] bf16.
// XOR swizzle: LDS[row][u] holds global 16B-unit u^(row&7) (pre-swizzled global source;
// linear global_load_lds dest). Counted vmcnt(4) at phases 4/8 only (T3+T4); setprio (T5).
// MODE 1: hb = relu(xg @ W1t^T + b1) (bf16) ; MODE 2: out[perm] = hb @ W2t^T + adj (f32)

__device__ __forceinline__ void stage_half(const ushort_t* __restrict__ gbase, int rstride,
                                           int row0, int rowmax, int kcol,
                                           ushort_t* ldsb, int wid, int l) {
#pragma unroll
  for (int r = 0; r < 2; ++r) {
    int idx = r * 512 + wid * 64 + l;
    int lrow = idx >> 3;
    int u = idx & 7;
    int grow = row0 + lrow;
    if (grow > rowmax) grow = rowmax;
    const ushort_t* src = gbase + (size_t)grow * rstride + kcol + ((u ^ (lrow & 7)) << 3);
    gload_lds16(src, ldsb + ((r * 512 + wid * 64) << 3));
  }
}

#define PHASE(bufc, mh, nh, VM, ...)                                                     \
  {                                                                                      \
    short8 af0[4], af1[4], bq0[2], bq1[2];                                               \
    const ushort_t* ha_ = &lds[bufc][mh][0];                                             \
    const ushort_t* hb_ = &lds[bufc][2 + (nh)][0];                                       \
    _Pragma("unroll")                                                                    \
    for (int i_ = 0; i_ < 4; ++i_) {                                                     \
      int ro_ = (wm * 64 + i_ * 16 + lr) * 64;                                           \
      af0[i_] = *(const short8*)&ha_[ro_ + ((lh ^ lx) << 3)];                            \
      af1[i_] = *(const short8*)&ha_[ro_ + (((4 + lh) ^ lx) << 3)];                      \
    }                                                                                    \
    _Pragma("unroll")                                                                    \
    for (int j_ = 0; j_ < 2; ++j_) {                                                     \
      int ro_ = (wn * 32 + j_ * 16 + lr) * 64;                                           \
      bq0[j_] = *(const short8*)&hb_[ro_ + ((lh ^ lx) << 3)];                            \
      bq1[j_] = *(const short8*)&hb_[ro_ + (((4 + lh) ^ lx) << 3)];                      \
    }                                                                                    \
    __VA_ARGS__;                                                                        \
    __builtin_amdgcn_s_barrier();                                                       \
    asm volatile("s_waitcnt lgkmcnt(0)" ::: "memory");                                  \
    __builtin_amdgcn_s_setprio(1);                                                      \
    _Pragma("unroll")                                                                    \
    for (int i_ = 0; i_ < 4; ++i_)                                                      \
      _Pragma("unroll")                                                                 \
      for (int j_ = 0; j_ < 2; ++j_)                                                    \
        acc[(mh) * 4 + i_][(nh) * 2 + j_] = __builtin_amdgcn_mfma_f32_16x16x32_bf16(    \
            af0[i_], bq0[j_], acc[(mh) * 4 + i_][(nh) * 2 + j_], 0, 0, 0);              \
    _Pragma("unroll")                                                                    \
    for (int i_ = 0; i_ < 4; ++i_)                                                      \
      _Pragma("unroll")                                                                 \
      for (int j_ = 0; j_ < 2; ++j_)                                                    \
        acc[(mh) * 4 + i_][(nh) * 2 + j_] = __builtin_amdgcn_mfma_f32_16x16x32_bf16(    \
            af1[i_], bq1[j_], acc[(mh) * 4 + i_][(nh) * 2 + j_], 0, 0, 0);              \
    __builtin_amdgcn_s_setprio(0);                                                      \
    if (VM) asm volatile("s_waitcnt vmcnt(4)" ::: "memory");                            \
    __builtin_amdgcn_s_barrier();                                                       \
  }

template <int MODE>
__global__ __launch_bounds__(512, 2) void ffn_gemm(
    const ushort_t* __restrict__ A_all, const ushort_t* __restrict__ Bw,
    const float* __restrict__ bias, const int* __restrict__ offs,
    const int* __restrict__ perm, float* __restrict__ out, ushort_t* __restrict__ hbo) {
  constexpr int Kd = (MODE == 1) ? D_ : H_;
  constexpr int Nd = (MODE == 1) ? H_ : D_;
  constexpr int TN = Nd / 256;
  constexpr int TM = NTOK / 256;  // 64
  constexpr int NKT = Kd / 64;
  const int e = blockIdx.y;
  const int ms = offs[e];
  const int M = offs[e + 1] - ms;
  // bijective XCD swizzle (grid.x = TM*TN divisible by 8), tm-fast decomposition
  const int bid = blockIdx.x;
  const int swz = (bid & 7) * ((TM * TN) >> 3) + (bid >> 3);
  const int tm = swz % TM;
  const int tn = swz / TM;
  if (tm * 256 >= M) return;

  __shared__ __align__(16) ushort_t lds[2][4][128 * 64];  // 128 KiB

  const int tid = threadIdx.x;
  const int wid = tid >> 6, l = tid & 63;
  const int wm = wid >> 2, wn = wid & 3;
  const int lr = l & 15, lh = l >> 4, lx = l & 7;

  const ushort_t* Ab = A_all + (size_t)ms * Kd;
  const ushort_t* Bb = Bw + (size_t)e * ((size_t)Nd * Kd);
  const int rowmaxA = M - 1;
  const int arow0 = tm * 256;
  const int brow0 = tn * 256;

  f32x4 acc[8][4];
#pragma unroll
  for (int i = 0; i < 8; ++i)
#pragma unroll
    for (int j = 0; j < 4; ++j) acc[i][j] = (f32x4){0.f, 0.f, 0.f, 0.f};

  // prologue: buf0 <- tile0 (all 4 halves), buf1 <- tile1 (A0,B0)
  stage_half(Ab, Kd, arow0 + 0,   rowmaxA, 0,  &lds[0][0][0], wid, l);
  stage_half(Bb, Kd, brow0 + 0,   Nd - 1,  0,  &lds[0][2][0], wid, l);
  stage_half(Ab, Kd, arow0 + 128, rowmaxA, 0,  &lds[0][1][0], wid, l);
  stage_half(Bb, Kd, brow0 + 128, Nd - 1,  0,  &lds[0][3][0], wid, l);
  stage_half(Ab, Kd, arow0 + 0,   rowmaxA, 64, &lds[1][0][0], wid, l);
  stage_half(Bb, Kd, brow0 + 0,   Nd - 1,  64, &lds[1][2][0], wid, l);
  asm volatile("s_waitcnt vmcnt(4)" ::: "memory");
  __builtin_amdgcn_s_barrier();

  for (int it = 0; it < NKT / 2; ++it) {
    const int k1 = (2 * it + 1) * 64;
    int t2 = 2 * it + 2; if (t2 > NKT - 1) t2 = NKT - 1;
    int t3 = 2 * it + 3; if (t3 > NKT - 1) t3 = NKT - 1;
    const int k2 = t2 * 64, k3 = t3 * 64;
    // ph1..ph4: compute buf0 (K-tile 2it); ph5..ph8: compute buf1 (K-tile 2it+1)
    PHASE(0, 0, 0, 0, stage_half(Ab, Kd, arow0 + 128, rowmaxA, k1, &lds[1][1][0], wid, l))
    PHASE(0, 0, 1, 0, stage_half(Bb, Kd, brow0 + 128, Nd - 1,  k1, &lds[1][3][0], wid, l))
    PHASE(0, 1, 0, 0, stage_half(Ab, Kd, arow0 + 0,   rowmaxA, k2, &lds[0][0][0], wid, l))
    PHASE(0, 1, 1, 1, stage_half(Bb, Kd, brow0 + 0,   Nd - 1,  k2, &lds[0][2][0], wid, l))
    PHASE(1, 0, 0, 0, stage_half(Ab, Kd, arow0 + 128, rowmaxA, k2, &lds[0][1][0], wid, l))
    PHASE(1, 0, 1, 0, stage_half(Bb, Kd, brow0 + 128, Nd - 1,  k2, &lds[0][3][0], wid, l))
    PHASE(1, 1, 0, 0, stage_half(Ab, Kd, arow0 + 0,   rowmaxA, k3, &lds[1][0][0], wid, l))
    PHASE(1, 1, 1, 1, stage_half(Bb, Kd, brow0 + 0,   Nd - 1,  k3, &lds[1][2][0], wid, l))
  }

  // epilogue: C[row = tm*256 + mh*128 + wm*64 + i*16 + lh*4 + rr]
  //            [col = tn*256 + nh*128 + wn*32 + j*16 + lr]
  float bv[4];
#pragma unroll
  for (int n = 0; n < 4; ++n)
    bv[n] = bias[e * Nd + tn * 256 + (n >> 1) * 128 + wn * 32 + (n & 1) * 16 + lr];
#pragma unroll
  for (int m = 0; m < 8; ++m) {
    const int mh = m >> 2, i = m & 3;
#pragma unroll
    for (int rr = 0; rr < 4; ++rr) {
      int grow = tm * 256 + mh * 128 + wm * 64 + i * 16 + lh * 4 + rr;
      if (grow < M) {
        if (MODE == 1) {
          size_t rowoff = (size_t)(ms + grow) * H_;
#pragma unroll
          for (int n = 0; n < 4; ++n) {
            float v = acc[m][n][rr] + bv[n];
            v = fmaxf(v, 0.f);
            hbo[rowoff + tn * 256 + (n >> 1) * 128 + wn * 32 + (n & 1) * 16 + lr] = f2bf(v);
          }
        } else {
          int tok = perm[ms + grow];
          size_t rowoff = (size_t)tok * D_;
#pragma unroll
          for (int n = 0; n < 4; ++n)
            out[rowoff + tn * 256 + (n >> 1) * 128 + wn * 32 + (n & 1) * 16 + lr] =
                acc[m][n][rr] + bv[n];
        }
      }
    }
  }
}

extern "C" void kernel_launch(void* const* d_in, const int* in_sizes, int n_in,
                              void* d_out, int out_size, void* d_ws, size_t ws_size,
                              hipStream_t stream) {
  const float* x  = (const float*)d_in[0];
  const float* W1 = (const float*)d_in[1];
  const float* b1 = (const float*)d_in[2];
  const float* W2 = (const float*)d_in[3];
  const float* b2 = (const float*)d_in[4];
  const float* Wr = (const float*)d_in[5];
  const float* br = (const float*)d_in[6];
  float* out = (float*)d_out;

  // workspace layout (needs ~302.3 MB)
  char* ws = (char*)d_ws;
  ushort_t* W1t   = (ushort_t*)(ws);                    // [E][H][D] bf16: 67108864 B
  ushort_t* W2t   = (ushort_t*)(ws + 67108864);         // [E][D][H] bf16: 67108864 B
  ushort_t* xg    = (ushort_t*)(ws + 134217728);        // [N][D]   bf16: 33554432 B
  ushort_t* hb    = (ushort_t*)(ws + 167772160);        // [N][H]   bf16: 134217728 B
  float*    rawbase = (float*)(ws + 301989888);         // [E][D] f32
  float*    adj   = (float*)(ws + 302022656);           // [E][D] f32
  int*      idx   = (int*)(ws + 302055424);             // [N]
  int*      perm  = (int*)(ws + 302120960);             // [N]
  int*      counts = (int*)(ws + 302186496);            // 8 + 8 cursor
  int*      cursor = counts + 8;
  int*      offsets = (int*)(ws + 302186624);           // 9

  init_kernel<<<32, 256, 0, stream>>>(counts, rawbase);
  transpose_bf16<<<dim3(H_ / 32, D_ / 32, E_), dim3(32, 8), 0, stream>>>(W1, W1t, D_, H_);
  transpose_bf16<<<dim3(D_ / 32, H_ / 32, E_), dim3(32, 8), 0, stream>>>(W2, W2t, H_, D_);
  base_kernel<<<dim3(4, E_, 8), 256, 0, stream>>>(b1, W2, rawbase);
  adj_kernel<<<32, 256, 0, stream>>>(rawbase, b2, adj);
  router_kernel<<<512, 256, 0, stream>>>(x, Wr, br, idx, counts);
  scan_kernel<<<1, 64, 0, stream>>>(counts, offsets);
  scatter_kernel<<<NTOK / 4, 256, 0, stream>>>(x, idx, offsets, cursor, perm, xg);
  ffn_gemm<1><<<dim3((NTOK / 256) * (H_ / 256), E_), dim3(512), 0, stream>>>(
      xg, W1t, b1, offsets, nullptr, nullptr, hb);
  ffn_gemm<2><<<dim3((NTOK / 256) * (D_ / 256), E_), dim3(512), 0, stream>>>(
      hb, W2t, adj, offsets, perm, out, nullptr);
}